// Round 9
// baseline (514.120 us; speedup 1.0000x reference)
//
#include <hip/hip_runtime.h>
#include <math.h>

// ---------------- problem constants (static graph/problem) ----------------
constexpr int NN   = 10000;          // nodes
constexpr int E0C  = 100000;         // edges without self loops
constexpr int EC   = E0C + NN;       // 110000 with self loops
constexpr int INC  = 512;
constexpr int HIDC = 256;
constexpr int OUTC = 10;
constexpr int H1C  = 4;
constexpr int H2C  = 1;
constexpr int ONC  = 2 * HIDC;       // 512
constexpr int D1C  = H1C * HIDC;     // 1024
constexpr int D2C  = H2C * HIDC;     // 256
constexpr int KC   = 5;
constexpr float LOG2PI_F = 1.8378770664093453f;

using u16 = unsigned short;
typedef __attribute__((ext_vector_type(8))) short bf16x8;
typedef __attribute__((ext_vector_type(4))) float f32x4;

// ---------------- helpers ----------------
__device__ __forceinline__ unsigned f2bf(float f) {
    unsigned u = __float_as_uint(f);
    return (u + 0x7fffu + ((u >> 16) & 1u)) >> 16;   // RNE
}
__device__ __forceinline__ float bflo(unsigned u) { return __uint_as_float(u << 16); }
__device__ __forceinline__ float bfhi(unsigned u) { return __uint_as_float(u & 0xffff0000u); }
__device__ __forceinline__ float bf1(u16 v) { return __uint_as_float(((unsigned)v) << 16); }
__device__ __forceinline__ void edge_sd(int e, const int* __restrict__ ei, int& src, int& dst) {
    if (e < E0C) { src = ei[e]; dst = ei[E0C + e]; }
    else         { src = e - E0C; dst = src; }
}
__device__ __forceinline__ float wmax(float x) {
#pragma unroll
    for (int o = 32; o > 0; o >>= 1) x = fmaxf(x, __shfl_xor(x, o, 64));
    return x;
}
__device__ __forceinline__ float wsum(float x) {
#pragma unroll
    for (int o = 32; o > 0; o >>= 1) x += __shfl_xor(x, o, 64);
    return x;
}

__global__ void zero_u32(unsigned* __restrict__ p, int n) {
    int i = blockIdx.x * blockDim.x + threadIdx.x;
    if (i < n) p[i] = 0u;
}

// ---------------- bf16 cast / transpose-cast ----------------
__global__ void cast_bf16(const float* __restrict__ in, u16* __restrict__ o, int n4) {
    int i = blockIdx.x * blockDim.x + threadIdx.x;
    if (i >= n4) return;
    float4 v = ((const float4*)in)[i];
    uint2 r;
    r.x = f2bf(v.x) | (f2bf(v.y) << 16);
    r.y = f2bf(v.z) | (f2bf(v.w) << 16);
    ((uint2*)o)[i] = r;
}

// W [K][N] fp32 -> WT [N][K] bf16
__global__ __launch_bounds__(256) void transpose_cast_bf16(const float* __restrict__ W,
                                                           u16* __restrict__ WT,
                                                           int K, int N) {
    __shared__ float tile[32][33];
    int n0 = blockIdx.x * 32, k0 = blockIdx.y * 32;
    int tx = threadIdx.x, ty = threadIdx.y;   // 32 x 8
    for (int r = ty; r < 32; r += 8) tile[r][tx] = W[(size_t)(k0 + r) * N + n0 + tx];
    __syncthreads();
    for (int r = ty; r < 32; r += 8) WT[(size_t)(n0 + r) * K + k0 + tx] = (u16)f2bf(tile[tx][r]);
}

// ---------------- graph preprocessing ----------------
__global__ void count_deg(const int* __restrict__ ei, int* __restrict__ deg) {
    int e = blockIdx.x * blockDim.x + threadIdx.x;
    if (e >= EC) return;
    int dst = (e < E0C) ? ei[E0C + e] : (e - E0C);
    atomicAdd(&deg[dst], 1);
}

__global__ __launch_bounds__(1024) void scan_kernel(const int* __restrict__ deg,
                                                    int* __restrict__ offs) {
    __shared__ int part[1024];
    const int CH = (NN + 1023) / 1024;   // 10
    int tid = threadIdx.x;
    int base = tid * CH;
    int s = 0;
    for (int i = 0; i < CH; i++) { int idx = base + i; if (idx < NN) s += deg[idx]; }
    part[tid] = s;
    __syncthreads();
    for (int o = 1; o < 1024; o <<= 1) {
        int v = (tid >= o) ? part[tid - o] : 0;
        __syncthreads();
        part[tid] += v;
        __syncthreads();
    }
    int run = (tid == 0) ? 0 : part[tid - 1];
    for (int i = 0; i < CH; i++) {
        int idx = base + i;
        if (idx < NN) {
            offs[idx] = run;
            run += deg[idx];
        }
    }
    if (tid == 1023) offs[NN] = run;
}

__global__ void csr_fill(const int* __restrict__ ei, int* __restrict__ cursor,
                         const int* __restrict__ offs, int* __restrict__ csr_src,
                         int* __restrict__ csr_eid) {
    int e = blockIdx.x * blockDim.x + threadIdx.x;
    if (e >= EC) return;
    int src, dst;
    edge_sd(e, ei, src, dst);
    int pos = offs[dst] + atomicAdd(&cursor[dst], 1);
    csr_src[pos] = src;
    csr_eid[pos] = e;
}

// ---------------- bf16 MFMA GEMM: C[M,N] = A[M,K] @ B[K,N], BT is [N][K] ----------------
template <int BM, int BN, int BK, bool BF16OUT>   // 128,128,32
__global__ __launch_bounds__(256) void mfma_gemm(const u16* __restrict__ A,
                                                 const u16* __restrict__ BT,
                                                 void* __restrict__ Cv,
                                                 int M, int N, int K) {
    constexpr int PK = BK + 16;      // keeps 16B alignment for ds_read_b128
    __shared__ __align__(16) u16 As[BM][PK];
    __shared__ __align__(16) u16 Bs[BN][PK];
    const int tid = threadIdx.x;
    const int lane = tid & 63;
    const int wave = tid >> 6;
    const int wm = (wave & 1) * 64;
    const int wn = (wave >> 1) * 64;
    const int row0 = blockIdx.y * BM;
    const int col0 = blockIdx.x * BN;

    f32x4 acc[4][4] = {};
    const int srow = tid >> 1;           // 0..127
    const int shalf = (tid & 1) * 16;    // 0 or 16 (bf16 elems)
    const int fr = lane & 15;
    const int fq = (lane >> 4) * 8;

    for (int k0 = 0; k0 < K; k0 += BK) {
        uint4 va0 = {0, 0, 0, 0}, va1 = {0, 0, 0, 0};
        int ga = row0 + srow;
        if (ga < M) {
            const uint4* p = (const uint4*)(A + (size_t)ga * K + k0 + shalf);
            va0 = p[0]; va1 = p[1];
        }
        const uint4* pb = (const uint4*)(BT + (size_t)(col0 + srow) * K + k0 + shalf);
        uint4 vb0 = pb[0], vb1 = pb[1];
        __syncthreads();
        *(uint4*)&As[srow][shalf]     = va0;
        *(uint4*)&As[srow][shalf + 8] = va1;
        *(uint4*)&Bs[srow][shalf]     = vb0;
        *(uint4*)&Bs[srow][shalf + 8] = vb1;
        __syncthreads();
        bf16x8 af[4], bfr[4];
#pragma unroll
        for (int i = 0; i < 4; i++) {
            af[i]  = *(const bf16x8*)&As[wm + i * 16 + fr][fq];
            bfr[i] = *(const bf16x8*)&Bs[wn + i * 16 + fr][fq];
        }
#pragma unroll
        for (int mi = 0; mi < 4; mi++)
#pragma unroll
            for (int ni = 0; ni < 4; ni++)
                acc[mi][ni] = __builtin_amdgcn_mfma_f32_16x16x32_bf16(af[mi], bfr[ni], acc[mi][ni], 0, 0, 0);
    }
    const int cc = lane & 15;
    const int cr = (lane >> 4) * 4;
#pragma unroll
    for (int mi = 0; mi < 4; mi++) {
#pragma unroll
        for (int r = 0; r < 4; r++) {
            int grow = row0 + wm + mi * 16 + cr + r;
            if (grow < M) {
#pragma unroll
                for (int ni = 0; ni < 4; ni++) {
                    int gcol = col0 + wn + ni * 16 + cc;
                    if (BF16OUT)
                        ((u16*)Cv)[(size_t)grow * N + gcol] = (u16)f2bf(acc[mi][ni][r]);
                    else
                        ((float*)Cv)[(size_t)grow * N + gcol] = acc[mi][ni][r];
                }
            }
        }
    }
}

// ---------------- attention scores (bf16 xh): one wave per (node, head) ----------------
template <int H>
__global__ __launch_bounds__(256) void scores_bf16(const u16* __restrict__ xh,
                                                   const float* __restrict__ att,
                                                   float* __restrict__ s_i,
                                                   float* __restrict__ s_j) {
    int gw = (blockIdx.x * 256 + threadIdx.x) >> 6;
    int lane = threadIdx.x & 63;
    if (gw >= NN * H) return;
    int n = gw / H, h = gw - n * H;
    const u16* xr = xh + ((size_t)n * H + h) * ONC;
    uint4 v = ((const uint4*)xr)[lane];                   // 8 bf16: channels lane*8..+8
    float xv[8] = { bflo(v.x), bfhi(v.x), bflo(v.y), bfhi(v.y),
                    bflo(v.z), bfhi(v.z), bflo(v.w), bfhi(v.w) };
    const float* base = att + (size_t)h * 2 * ONC;
    const float4* aL = (const float4*)(base + lane * 8);
    const float4* aR = (const float4*)(base + ONC + lane * 8);
    float4 l0 = aL[0], l1 = aL[1], r0 = aR[0], r1 = aR[1];
    float ai = xv[0] * l0.x + xv[1] * l0.y + xv[2] * l0.z + xv[3] * l0.w
             + xv[4] * l1.x + xv[5] * l1.y + xv[6] * l1.z + xv[7] * l1.w;
    float aj = xv[0] * r0.x + xv[1] * r0.y + xv[2] * r0.z + xv[3] * r0.w
             + xv[4] * r1.x + xv[5] * r1.y + xv[6] * r1.z + xv[7] * r1.w;
#pragma unroll
    for (int o = 32; o > 0; o >>= 1) {
        ai += __shfl_down(ai, o, 64);
        aj += __shfl_down(aj, o, 64);
    }
    if (lane == 0) { s_i[gw] = ai; s_j[gw] = aj; }
}

// ---------------- fused per-segment attention softmax ----------------
template <int H, int PW>
__global__ __launch_bounds__(256) void attn_fused(const int* __restrict__ offs,
                                                  const int* __restrict__ csr_src,
                                                  const int* __restrict__ csr_eid,
                                                  const float* __restrict__ s_i,
                                                  const float* __restrict__ s_j,
                                                  const float* __restrict__ g,
                                                  float* __restrict__ alpha_csr,
                                                  float* __restrict__ kl_acc,
                                                  float scale) {
    const int tid = threadIdx.x;
    const int wave = tid >> 6, lane = tid & 63;
    const int pair0 = (blockIdx.x * 4 + wave) * PW;
    float kl = 0.f;
#pragma unroll 1
    for (int t = 0; t < PW; t++) {
        int pr = pair0 + t;
        if (pr >= NN * H) break;
        int n = pr / H, h = pr - (pr / H) * H;
        int beg = offs[n], end = offs[n + 1];
        int deg = end - beg;
        float si = s_i[n * H + h];
        float ldeg = __logf((float)deg);
        if (deg <= 64) {
            int pos = beg + lane;
            bool v = lane < deg;
            int src = v ? csr_src[pos] : 0;
            int eid = v ? csr_eid[pos] : 0;
            float a = si + s_j[src * H + h];
            a = (a > 0.f) ? a : 0.2f * a;
            if (!v) a = -3.4e38f;
            float m1 = wmax(a);
            float am = v ? (a - m1) : 0.f;
            float e1 = v ? __expf(am) : 0.f;
            float ss1 = wsum(e1);
            float sd  = wsum(e1 * am);
            float lss1 = __logf(ss1);
            kl += sd / ss1 - lss1 + ldeg;
            float l2 = v ? (am - lss1 + g[eid * H + h]) : -3.4e38f;
            float m2 = wmax(l2);
            float e2 = v ? __expf(l2 - m2) : 0.f;
            float ss2 = wsum(e2);
            if (v) alpha_csr[(size_t)pos * H + h] = e2 / ss2;
        } else {
            float m1 = -3.4e38f;
            for (int p = beg + lane; p < end; p += 64) {
                float a = si + s_j[csr_src[p] * H + h];
                a = (a > 0.f) ? a : 0.2f * a;
                m1 = fmaxf(m1, a);
            }
            m1 = wmax(m1);
            float ss1 = 0.f, sd = 0.f;
            for (int p = beg + lane; p < end; p += 64) {
                float a = si + s_j[csr_src[p] * H + h];
                a = (a > 0.f) ? a : 0.2f * a;
                float e1 = __expf(a - m1);
                ss1 += e1; sd += e1 * (a - m1);
            }
            ss1 = wsum(ss1); sd = wsum(sd);
            float lss1 = __logf(ss1);
            kl += sd / ss1 - lss1 + ldeg;
            float m2 = -3.4e38f;
            for (int p = beg + lane; p < end; p += 64) {
                float a = si + s_j[csr_src[p] * H + h];
                a = (a > 0.f) ? a : 0.2f * a;
                m2 = fmaxf(m2, a - m1 - lss1 + g[csr_eid[p] * H + h]);
            }
            m2 = wmax(m2);
            float ss2 = 0.f;
            for (int p = beg + lane; p < end; p += 64) {
                float a = si + s_j[csr_src[p] * H + h];
                a = (a > 0.f) ? a : 0.2f * a;
                ss2 += __expf(a - m1 - lss1 + g[csr_eid[p] * H + h] - m2);
            }
            ss2 = wsum(ss2);
            for (int p = beg + lane; p < end; p += 64) {
                float a = si + s_j[csr_src[p] * H + h];
                a = (a > 0.f) ? a : 0.2f * a;
                alpha_csr[(size_t)p * H + h] =
                    __expf(a - m1 - lss1 + g[csr_eid[p] * H + h] - m2) / ss2;
            }
        }
    }
    __shared__ float red[4];
    if (lane == 0) red[wave] = kl;
    __syncthreads();
    if (tid == 0)
        atomicAdd(kl_acc, (red[0] + red[1] + red[2] + red[3]) * scale);
}

// ---------------- FUSED panel-pinned gather + Z/elu/log_q/mixture/ixz ----------------
// d-space panels: panel p owns d in [p*DPP, (p+1)*DPP), DPP=128. Each lane
// accumulates 4 mean + 4 raw channels in fp32 regs (two 8B loads/edge), then
// runs the reparam/mixture epilogue directly — no intermediate buffer.
// 2 nodes per wave (32 lanes each), 8 nodes per block, edge loop unroll 8.
template <int H, int NP, bool BF16OUT>
__global__ __launch_bounds__(256) void gather_zixz(const u16* __restrict__ xh,
                                                   const float* __restrict__ alpha_csr,
                                                   const int* __restrict__ offs,
                                                   const int* __restrict__ csr_src,
                                                   const float* __restrict__ eps,
                                                   const float* __restrict__ tab,
                                                   void* __restrict__ hout_,
                                                   float* __restrict__ ixz_acc) {
    constexpr int ROW = H * ONC;
    constexpr int D   = H * HIDC;
    constexpr int DPP = D / NP;       // 128 d-channels per panel
    constexpr int DK  = D * KC;
    const int bx = blockIdx.x;
    const int panel = bx % NP;
    const int wave = threadIdx.x >> 6;
    const int lane = threadIdx.x & 63;
    const int half = lane >> 5;
    const int l32  = lane & 31;
    const int n = (bx / NP) * 8 + wave * 2 + half;
    const int d0 = panel * DPP + l32 * 4;         // 4 d-channels per lane
    const int head = d0 / HIDC;
    const int c = d0 - head * HIDC;               // within-head channel
    const int moff = head * ONC + c;              // mean offset in xh row
    const int beg = offs[n], end = offs[n + 1];
    const int deg = end - beg;
    const int degO = __shfl_xor(deg, 32, 64);
    const int mdeg = max(deg, degO);
    const int bsel = half << 5;
    float accM[4] = {0.f, 0.f, 0.f, 0.f};
    float accR[4] = {0.f, 0.f, 0.f, 0.f};
    for (int cc0 = 0; cc0 < mdeg; cc0 += 32) {
        bool v = (cc0 + l32) < deg;
        int myp = beg + cc0 + l32;
        int   srcv = v ? csr_src[myp] : 0;
        float wv   = v ? alpha_csr[(size_t)myp * H + head] : 0.f;
        int cnt = min(32, mdeg - cc0);
#pragma unroll 8
        for (int t = 0; t < cnt; t++) {
            int   s = __shfl(srcv, bsel + t, 64);
            float w = __shfl(wv,   bsel + t, 64);
            const u16* xr = xh + (size_t)s * ROW + moff;
            uint2 vm = *(const uint2*)xr;
            uint2 vr = *(const uint2*)(xr + HIDC);
            accM[0] = fmaf(w, bflo(vm.x), accM[0]);
            accM[1] = fmaf(w, bfhi(vm.x), accM[1]);
            accM[2] = fmaf(w, bflo(vm.y), accM[2]);
            accM[3] = fmaf(w, bfhi(vm.y), accM[3]);
            accR[0] = fmaf(w, bflo(vr.x), accR[0]);
            accR[1] = fmaf(w, bfhi(vr.x), accR[1]);
            accR[2] = fmaf(w, bflo(vr.y), accR[2]);
            accR[3] = fmaf(w, bfhi(vr.y), accR[3]);
        }
    }
    // ---- epilogue: reparam + mixture prior, ixz partial ----
    float4 ep4 = *(const float4*)(eps + (size_t)n * D + d0);
    float eq[4] = { ep4.x, ep4.y, ep4.z, ep4.w };
    float hv4[4];
    float local = 0.f;
#pragma unroll
    for (int j = 0; j < 4; j++) {
        int d = d0 + j;
        float raw = accR[j];
        float sp = fmaxf(raw, 0.f) + __logf(1.f + __expf(-fabsf(raw)));
        float stdv = sp + 1e-10f;
        float ep = eq[j];
        float Z = fmaf(stdv, ep, accM[j]);
        hv4[j] = (Z > 0.f) ? Z : (__expf(Z) - 1.f);
        float logq = fmaf(-0.5f, ep * ep, -__logf(stdv)) - 0.5f * LOG2PI_F;
        float comp[KC]; float mx = -3.4e38f;
#pragma unroll
        for (int k = 0; k < KC; k++) {
            float ca = tab[d * KC + k];
            float cb = tab[DK + d * KC + k];
            float cv = tab[2 * DK + d * KC + k];
            float cval = fmaf(fmaf(ca, Z, cb), Z, cv);
            comp[k] = cval;
            mx = fmaxf(mx, cval);
        }
        float se = 0.f;
#pragma unroll
        for (int k = 0; k < KC; k++) se += __expf(comp[k] - mx);
        local += logq - (mx + __logf(se));
    }
    if (BF16OUT) {
        uint2 r;
        r.x = f2bf(hv4[0]) | (f2bf(hv4[1]) << 16);
        r.y = f2bf(hv4[2]) | (f2bf(hv4[3]) << 16);
        *(uint2*)((u16*)hout_ + (size_t)n * D + d0) = r;
    } else {
        *(float4*)((float*)hout_ + (size_t)n * D + d0) = make_float4(hv4[0], hv4[1], hv4[2], hv4[3]);
    }
    // reduce within each 32-lane half, then block, then one atomic
#pragma unroll
    for (int o = 16; o > 0; o >>= 1) local += __shfl_xor(local, o, 64);
    __shared__ float red[8];
    if (l32 == 0) red[wave * 2 + half] = local;
    __syncthreads();
    if (threadIdx.x == 0) {
        float s = 0.f;
#pragma unroll
        for (int i = 0; i < 8; i++) s += red[i];
        atomicAdd(ixz_acc, s * (1.0f / NN));
    }
}

// ---------------- mixture-prior quadratic table: comp_k(Z) = (a*Z + b)*Z + c ----------------
__global__ void mix_table(const float* __restrict__ pi, const float* __restrict__ mu,
                          const float* __restrict__ logsig, float* __restrict__ tab, int DK) {
    int i = blockIdx.x * blockDim.x + threadIdx.x;
    if (i >= DK) return;
    int k = i % KC;
    float p[KC]; float mx = -3.4e38f;
#pragma unroll
    for (int j = 0; j < KC; j++) { p[j] = pi[j]; mx = fmaxf(mx, p[j]); }
    float s = 0.f;
#pragma unroll
    for (int j = 0; j < KC; j++) s += expf(p[j] - mx);
    float lpi = p[k] - (mx + logf(s));
    float ls = logsig[i];
    float inv = expf(-ls);
    float inv2 = inv * inv;
    float m = mu[i];
    tab[i]          = -0.5f * inv2;                                      // a
    tab[DK + i]     = inv2 * m;                                          // b
    tab[2 * DK + i] = -0.5f * inv2 * m * m - ls - 0.5f * LOG2PI_F + lpi; // c
}

// ---------------- final FC ----------------
__global__ void fc_kernel(const float* __restrict__ h, const float* __restrict__ W,
                          const float* __restrict__ b, float* __restrict__ out) {
    int idx = blockIdx.x * blockDim.x + threadIdx.x;
    if (idx >= NN * OUTC) return;
    int n = idx / OUTC, o = idx - n * OUTC;
    const float* hr = h + (size_t)n * D2C;
    float acc = b[o];
#pragma unroll 8
    for (int c = 0; c < D2C; c++) acc += hr[c] * W[c * OUTC + o];
    out[idx] = acc;
}

// ---------------- launch ----------------
extern "C" void kernel_launch(void* const* d_in, const int* in_sizes, int n_in,
                              void* d_out, int out_size, void* d_ws, size_t ws_size,
                              hipStream_t stream) {
    (void)in_sizes; (void)n_in; (void)out_size; (void)ws_size;
    const float* x       = (const float*)d_in[0];
    const int*   ei      = (const int*)d_in[1];
    const float* W1      = (const float*)d_in[2];
    const float* att1    = (const float*)d_in[3];
    const float* pi1     = (const float*)d_in[4];
    const float* mu1     = (const float*)d_in[5];
    const float* logsig1 = (const float*)d_in[6];
    const float* eps1    = (const float*)d_in[7];
    const float* g1      = (const float*)d_in[8];
    const float* W2      = (const float*)d_in[9];
    const float* att2    = (const float*)d_in[10];
    const float* pi2     = (const float*)d_in[11];
    const float* mu2     = (const float*)d_in[12];
    const float* logsig2 = (const float*)d_in[13];
    const float* eps2    = (const float*)d_in[14];
    const float* g2      = (const float*)d_in[15];
    const float* Wfc     = (const float*)d_in[16];
    const float* bfc     = (const float*)d_in[17];
    float* out = (float*)d_out;

    // workspace layout
    char* ws = (char*)d_ws;
    const size_t szAB = (size_t)NN * 2048 * sizeof(float);
    char* regA = ws;
    char* regB = ws + szAB;
    size_t cur = 2 * szAB;
    auto alloc = [&](size_t bytes) -> char* {
        char* p = ws + cur;
        cur += (bytes + 255) & ~(size_t)255;
        return p;
    };
    float* alphaB   = (float*)alloc((size_t)EC * H1C * sizeof(float));  // CSR-order alpha
    float* s_i      = (float*)alloc((size_t)NN * H1C * sizeof(float));
    float* s_j      = (float*)alloc((size_t)NN * H1C * sizeof(float));
    int*   deg_i    = (int*)alloc(NN * sizeof(int));
    int*   offs     = (int*)alloc((NN + 1) * sizeof(int));
    int*   cursor   = (int*)alloc(NN * sizeof(int));
    int*   csr_src  = (int*)alloc(EC * sizeof(int));
    int*   csr_eid  = (int*)alloc(EC * sizeof(int));
    u16*   xb1     = (u16*)alloc((size_t)NN * INC * sizeof(u16));      // x in bf16
    u16*   w1t     = (u16*)alloc((size_t)2048 * 512 * sizeof(u16));    // W1^T bf16 [N][K]
    u16*   w2t     = (u16*)alloc((size_t)512 * 1024 * sizeof(u16));    // W2^T bf16 [N][K]
    float* tab1    = (float*)alloc((size_t)3 * D1C * KC * sizeof(float));
    float* tab2    = (float*)alloc((size_t)3 * D2C * KC * sizeof(float));

    // region assignments (stream-ordered reuse; fused kernel reads xh while
    // writing h, so xh and h must NOT alias):
    u16*   xh1b = (u16*)regA;       // N x 2048 bf16 (GEMM1 out)
    u16*   h1b  = (u16*)regB;       // N x 1024 bf16 (gather_zixz1 out)
    u16*   xh2b = (u16*)regA;       // N x 512 bf16 (GEMM2 out; xh1b dead)
    float* h2   = (float*)regB;     // N x 256 fp32 (gather_zixz2 out; h1b dead)
    float* kl_acc  = out + (size_t)NN * OUTC;      // d_out[100000]
    float* ixz_acc = kl_acc + 1;                   // d_out[100001]

    const int ZB = 256;
    // --- init accumulators / counters ---
    zero_u32<<<(NN + ZB - 1) / ZB, ZB, 0, stream>>>((unsigned*)deg_i, NN);
    zero_u32<<<(NN + ZB - 1) / ZB, ZB, 0, stream>>>((unsigned*)cursor, NN);
    zero_u32<<<1, ZB, 0, stream>>>((unsigned*)kl_acc, 2);

    // --- graph preprocessing (shared by both layers) ---
    count_deg<<<(EC + ZB - 1) / ZB, ZB, 0, stream>>>(ei, deg_i);
    scan_kernel<<<1, 1024, 0, stream>>>(deg_i, offs);
    csr_fill<<<(EC + ZB - 1) / ZB, ZB, 0, stream>>>(ei, cursor, offs, csr_src, csr_eid);

    // --- bf16 weight/input preparation + mixture tables ---
    cast_bf16<<<(NN * INC / 4 + ZB - 1) / ZB, ZB, 0, stream>>>(x, xb1, NN * INC / 4);
    transpose_cast_bf16<<<dim3(2048 / 32, 512 / 32), dim3(32, 8), 0, stream>>>(W1, w1t, 512, 2048);
    transpose_cast_bf16<<<dim3(512 / 32, 1024 / 32), dim3(32, 8), 0, stream>>>(W2, w2t, 1024, 512);
    mix_table<<<(D1C * KC + ZB - 1) / ZB, ZB, 0, stream>>>(pi1, mu1, logsig1, tab1, D1C * KC);
    mix_table<<<(D2C * KC + ZB - 1) / ZB, ZB, 0, stream>>>(pi2, mu2, logsig2, tab2, D2C * KC);

    const int MG = (NN + 127) / 128;   // 79

    // ================= layer 1 (H=4) =================
    mfma_gemm<128, 128, 32, true><<<dim3(2048 / 128, MG), 256, 0, stream>>>(xb1, w1t, xh1b, NN, 2048, 512);
    scores_bf16<H1C><<<(NN * H1C + 3) / 4, 256, 0, stream>>>(xh1b, att1, s_i, s_j);
    attn_fused<H1C, 8><<<(NN * H1C + 31) / 32, 256, 0, stream>>>(offs, csr_src, csr_eid,
                                                                 s_i, s_j, g1, alphaB, kl_acc,
                                                                 1.0f / (float)(EC * H1C));
    gather_zixz<H1C, 8, true><<<8 * (NN / 8), 256, 0, stream>>>(xh1b, alphaB, offs, csr_src,
                                                                eps1, tab1, (void*)h1b, ixz_acc);

    // ================= layer 2 (H=1) =================
    mfma_gemm<128, 128, 32, true><<<dim3(512 / 128, MG), 256, 0, stream>>>(h1b, w2t, xh2b, NN, 512, 1024);
    scores_bf16<H2C><<<(NN * H2C + 3) / 4, 256, 0, stream>>>(xh2b, att2, s_i, s_j);
    attn_fused<H2C, 8><<<(NN * H2C + 31) / 32, 256, 0, stream>>>(offs, csr_src, csr_eid,
                                                                 s_i, s_j, g2, alphaB, kl_acc,
                                                                 1.0f / (float)(EC * H2C));
    gather_zixz<H2C, 2, false><<<2 * (NN / 8), 256, 0, stream>>>(xh2b, alphaB, offs, csr_src,
                                                                 eps2, tab2, (void*)h2, ixz_acc);

    // ================= FC head =================
    fc_kernel<<<(NN * OUTC + ZB - 1) / ZB, ZB, 0, stream>>>(h2, Wfc, bfc, out);
}

// Round 10
// 433.125 us; speedup vs baseline: 1.1870x; 1.1870x over previous
//
#include <hip/hip_runtime.h>
#include <math.h>

// ---------------- problem constants (static graph/problem) ----------------
constexpr int NN   = 10000;          // nodes
constexpr int E0C  = 100000;         // edges without self loops
constexpr int EC   = E0C + NN;       // 110000 with self loops
constexpr int INC  = 512;
constexpr int HIDC = 256;
constexpr int OUTC = 10;
constexpr int H1C  = 4;
constexpr int H2C  = 1;
constexpr int ONC  = 2 * HIDC;       // 512
constexpr int D1C  = H1C * HIDC;     // 1024
constexpr int D2C  = H2C * HIDC;     // 256
constexpr int KC   = 5;
constexpr float LOG2PI_F = 1.8378770664093453f;

using u16 = unsigned short;
typedef __attribute__((ext_vector_type(8))) short bf16x8;
typedef __attribute__((ext_vector_type(4))) float f32x4;

// ---------------- helpers ----------------
__device__ __forceinline__ unsigned f2bf(float f) {
    unsigned u = __float_as_uint(f);
    return (u + 0x7fffu + ((u >> 16) & 1u)) >> 16;   // RNE
}
__device__ __forceinline__ float bflo(unsigned u) { return __uint_as_float(u << 16); }
__device__ __forceinline__ float bfhi(unsigned u) { return __uint_as_float(u & 0xffff0000u); }
__device__ __forceinline__ float bf1(u16 v) { return __uint_as_float(((unsigned)v) << 16); }
__device__ __forceinline__ void edge_sd(int e, const int* __restrict__ ei, int& src, int& dst) {
    if (e < E0C) { src = ei[e]; dst = ei[E0C + e]; }
    else         { src = e - E0C; dst = src; }
}
__device__ __forceinline__ float wmax(float x) {
#pragma unroll
    for (int o = 32; o > 0; o >>= 1) x = fmaxf(x, __shfl_xor(x, o, 64));
    return x;
}
__device__ __forceinline__ float wsum(float x) {
#pragma unroll
    for (int o = 32; o > 0; o >>= 1) x += __shfl_xor(x, o, 64);
    return x;
}

__global__ void zero_u32(unsigned* __restrict__ p, int n) {
    int i = blockIdx.x * blockDim.x + threadIdx.x;
    if (i < n) p[i] = 0u;
}

// ---------------- bf16 cast / transpose-cast ----------------
__global__ void cast_bf16(const float* __restrict__ in, u16* __restrict__ o, int n4) {
    int i = blockIdx.x * blockDim.x + threadIdx.x;
    if (i >= n4) return;
    float4 v = ((const float4*)in)[i];
    uint2 r;
    r.x = f2bf(v.x) | (f2bf(v.y) << 16);
    r.y = f2bf(v.z) | (f2bf(v.w) << 16);
    ((uint2*)o)[i] = r;
}

// W [K][N] fp32 -> WT [N][K] bf16
__global__ __launch_bounds__(256) void transpose_cast_bf16(const float* __restrict__ W,
                                                           u16* __restrict__ WT,
                                                           int K, int N) {
    __shared__ float tile[32][33];
    int n0 = blockIdx.x * 32, k0 = blockIdx.y * 32;
    int tx = threadIdx.x, ty = threadIdx.y;   // 32 x 8
    for (int r = ty; r < 32; r += 8) tile[r][tx] = W[(size_t)(k0 + r) * N + n0 + tx];
    __syncthreads();
    for (int r = ty; r < 32; r += 8) WT[(size_t)(n0 + r) * K + k0 + tx] = (u16)f2bf(tile[tx][r]);
}

// ---------------- graph preprocessing ----------------
__global__ void count_deg(const int* __restrict__ ei, int* __restrict__ deg) {
    int e = blockIdx.x * blockDim.x + threadIdx.x;
    if (e >= EC) return;
    int dst = (e < E0C) ? ei[E0C + e] : (e - E0C);
    atomicAdd(&deg[dst], 1);
}

__global__ __launch_bounds__(1024) void scan_kernel(const int* __restrict__ deg,
                                                    int* __restrict__ offs) {
    __shared__ int part[1024];
    const int CH = (NN + 1023) / 1024;   // 10
    int tid = threadIdx.x;
    int base = tid * CH;
    int s = 0;
    for (int i = 0; i < CH; i++) { int idx = base + i; if (idx < NN) s += deg[idx]; }
    part[tid] = s;
    __syncthreads();
    for (int o = 1; o < 1024; o <<= 1) {
        int v = (tid >= o) ? part[tid - o] : 0;
        __syncthreads();
        part[tid] += v;
        __syncthreads();
    }
    int run = (tid == 0) ? 0 : part[tid - 1];
    for (int i = 0; i < CH; i++) {
        int idx = base + i;
        if (idx < NN) {
            offs[idx] = run;
            run += deg[idx];
        }
    }
    if (tid == 1023) offs[NN] = run;
}

__global__ void csr_fill(const int* __restrict__ ei, int* __restrict__ cursor,
                         const int* __restrict__ offs, int* __restrict__ csr_src,
                         int* __restrict__ csr_eid) {
    int e = blockIdx.x * blockDim.x + threadIdx.x;
    if (e >= EC) return;
    int src, dst;
    edge_sd(e, ei, src, dst);
    int pos = offs[dst] + atomicAdd(&cursor[dst], 1);
    csr_src[pos] = src;
    csr_eid[pos] = e;
}

// ---------------- bf16 MFMA GEMM: C[M,N] = A[M,K] @ B[K,N], BT is [N][K] ----------------
template <int BM, int BN, int BK, bool BF16OUT>   // 128,128,32
__global__ __launch_bounds__(256) void mfma_gemm(const u16* __restrict__ A,
                                                 const u16* __restrict__ BT,
                                                 void* __restrict__ Cv,
                                                 int M, int N, int K) {
    constexpr int PK = BK + 16;      // keeps 16B alignment for ds_read_b128
    __shared__ __align__(16) u16 As[BM][PK];
    __shared__ __align__(16) u16 Bs[BN][PK];
    const int tid = threadIdx.x;
    const int lane = tid & 63;
    const int wave = tid >> 6;
    const int wm = (wave & 1) * 64;
    const int wn = (wave >> 1) * 64;
    const int row0 = blockIdx.y * BM;
    const int col0 = blockIdx.x * BN;

    f32x4 acc[4][4] = {};
    const int srow = tid >> 1;           // 0..127
    const int shalf = (tid & 1) * 16;    // 0 or 16 (bf16 elems)
    const int fr = lane & 15;
    const int fq = (lane >> 4) * 8;

    for (int k0 = 0; k0 < K; k0 += BK) {
        uint4 va0 = {0, 0, 0, 0}, va1 = {0, 0, 0, 0};
        int ga = row0 + srow;
        if (ga < M) {
            const uint4* p = (const uint4*)(A + (size_t)ga * K + k0 + shalf);
            va0 = p[0]; va1 = p[1];
        }
        const uint4* pb = (const uint4*)(BT + (size_t)(col0 + srow) * K + k0 + shalf);
        uint4 vb0 = pb[0], vb1 = pb[1];
        __syncthreads();
        *(uint4*)&As[srow][shalf]     = va0;
        *(uint4*)&As[srow][shalf + 8] = va1;
        *(uint4*)&Bs[srow][shalf]     = vb0;
        *(uint4*)&Bs[srow][shalf + 8] = vb1;
        __syncthreads();
        bf16x8 af[4], bfr[4];
#pragma unroll
        for (int i = 0; i < 4; i++) {
            af[i]  = *(const bf16x8*)&As[wm + i * 16 + fr][fq];
            bfr[i] = *(const bf16x8*)&Bs[wn + i * 16 + fr][fq];
        }
#pragma unroll
        for (int mi = 0; mi < 4; mi++)
#pragma unroll
            for (int ni = 0; ni < 4; ni++)
                acc[mi][ni] = __builtin_amdgcn_mfma_f32_16x16x32_bf16(af[mi], bfr[ni], acc[mi][ni], 0, 0, 0);
    }
    const int cc = lane & 15;
    const int cr = (lane >> 4) * 4;
#pragma unroll
    for (int mi = 0; mi < 4; mi++) {
#pragma unroll
        for (int r = 0; r < 4; r++) {
            int grow = row0 + wm + mi * 16 + cr + r;
            if (grow < M) {
#pragma unroll
                for (int ni = 0; ni < 4; ni++) {
                    int gcol = col0 + wn + ni * 16 + cc;
                    if (BF16OUT)
                        ((u16*)Cv)[(size_t)grow * N + gcol] = (u16)f2bf(acc[mi][ni][r]);
                    else
                        ((float*)Cv)[(size_t)grow * N + gcol] = acc[mi][ni][r];
                }
            }
        }
    }
}

// ---------------- attention scores (bf16 xh): one wave per (node, head) ----------------
template <int H>
__global__ __launch_bounds__(256) void scores_bf16(const u16* __restrict__ xh,
                                                   const float* __restrict__ att,
                                                   float* __restrict__ s_i,
                                                   float* __restrict__ s_j) {
    int gw = (blockIdx.x * 256 + threadIdx.x) >> 6;
    int lane = threadIdx.x & 63;
    if (gw >= NN * H) return;
    int n = gw / H, h = gw - n * H;
    const u16* xr = xh + ((size_t)n * H + h) * ONC;
    uint4 v = ((const uint4*)xr)[lane];                   // 8 bf16: channels lane*8..+8
    float xv[8] = { bflo(v.x), bfhi(v.x), bflo(v.y), bfhi(v.y),
                    bflo(v.z), bfhi(v.z), bflo(v.w), bfhi(v.w) };
    const float* base = att + (size_t)h * 2 * ONC;
    const float4* aL = (const float4*)(base + lane * 8);
    const float4* aR = (const float4*)(base + ONC + lane * 8);
    float4 l0 = aL[0], l1 = aL[1], r0 = aR[0], r1 = aR[1];
    float ai = xv[0] * l0.x + xv[1] * l0.y + xv[2] * l0.z + xv[3] * l0.w
             + xv[4] * l1.x + xv[5] * l1.y + xv[6] * l1.z + xv[7] * l1.w;
    float aj = xv[0] * r0.x + xv[1] * r0.y + xv[2] * r0.z + xv[3] * r0.w
             + xv[4] * r1.x + xv[5] * r1.y + xv[6] * r1.z + xv[7] * r1.w;
#pragma unroll
    for (int o = 32; o > 0; o >>= 1) {
        ai += __shfl_down(ai, o, 64);
        aj += __shfl_down(aj, o, 64);
    }
    if (lane == 0) { s_i[gw] = ai; s_j[gw] = aj; }
}

// ---------------- fused per-segment attention softmax ----------------
template <int H, int PW>
__global__ __launch_bounds__(256) void attn_fused(const int* __restrict__ offs,
                                                  const int* __restrict__ csr_src,
                                                  const int* __restrict__ csr_eid,
                                                  const float* __restrict__ s_i,
                                                  const float* __restrict__ s_j,
                                                  const float* __restrict__ g,
                                                  float* __restrict__ alpha_csr,
                                                  float* __restrict__ kl_acc,
                                                  float scale) {
    const int tid = threadIdx.x;
    const int wave = tid >> 6, lane = tid & 63;
    const int pair0 = (blockIdx.x * 4 + wave) * PW;
    float kl = 0.f;
#pragma unroll 1
    for (int t = 0; t < PW; t++) {
        int pr = pair0 + t;
        if (pr >= NN * H) break;
        int n = pr / H, h = pr - (pr / H) * H;
        int beg = offs[n], end = offs[n + 1];
        int deg = end - beg;
        float si = s_i[n * H + h];
        float ldeg = __logf((float)deg);
        if (deg <= 64) {
            int pos = beg + lane;
            bool v = lane < deg;
            int src = v ? csr_src[pos] : 0;
            int eid = v ? csr_eid[pos] : 0;
            float a = si + s_j[src * H + h];
            a = (a > 0.f) ? a : 0.2f * a;
            if (!v) a = -3.4e38f;
            float m1 = wmax(a);
            float am = v ? (a - m1) : 0.f;
            float e1 = v ? __expf(am) : 0.f;
            float ss1 = wsum(e1);
            float sd  = wsum(e1 * am);
            float lss1 = __logf(ss1);
            kl += sd / ss1 - lss1 + ldeg;
            float l2 = v ? (am - lss1 + g[eid * H + h]) : -3.4e38f;
            float m2 = wmax(l2);
            float e2 = v ? __expf(l2 - m2) : 0.f;
            float ss2 = wsum(e2);
            if (v) alpha_csr[(size_t)pos * H + h] = e2 / ss2;
        } else {
            float m1 = -3.4e38f;
            for (int p = beg + lane; p < end; p += 64) {
                float a = si + s_j[csr_src[p] * H + h];
                a = (a > 0.f) ? a : 0.2f * a;
                m1 = fmaxf(m1, a);
            }
            m1 = wmax(m1);
            float ss1 = 0.f, sd = 0.f;
            for (int p = beg + lane; p < end; p += 64) {
                float a = si + s_j[csr_src[p] * H + h];
                a = (a > 0.f) ? a : 0.2f * a;
                float e1 = __expf(a - m1);
                ss1 += e1; sd += e1 * (a - m1);
            }
            ss1 = wsum(ss1); sd = wsum(sd);
            float lss1 = __logf(ss1);
            kl += sd / ss1 - lss1 + ldeg;
            float m2 = -3.4e38f;
            for (int p = beg + lane; p < end; p += 64) {
                float a = si + s_j[csr_src[p] * H + h];
                a = (a > 0.f) ? a : 0.2f * a;
                m2 = fmaxf(m2, a - m1 - lss1 + g[csr_eid[p] * H + h]);
            }
            m2 = wmax(m2);
            float ss2 = 0.f;
            for (int p = beg + lane; p < end; p += 64) {
                float a = si + s_j[csr_src[p] * H + h];
                a = (a > 0.f) ? a : 0.2f * a;
                ss2 += __expf(a - m1 - lss1 + g[csr_eid[p] * H + h] - m2);
            }
            ss2 = wsum(ss2);
            for (int p = beg + lane; p < end; p += 64) {
                float a = si + s_j[csr_src[p] * H + h];
                a = (a > 0.f) ? a : 0.2f * a;
                alpha_csr[(size_t)p * H + h] =
                    __expf(a - m1 - lss1 + g[csr_eid[p] * H + h] - m2) / ss2;
            }
        }
    }
    __shared__ float red[4];
    if (lane == 0) red[wave] = kl;
    __syncthreads();
    if (tid == 0)
        atomicAdd(kl_acc, (red[0] + red[1] + red[2] + red[3]) * scale);
}

// ---------------- panel-pinned CSR gather: 2 nodes/wave, 16B/lane, unroll 8 ----------------
template <int H, int NP>
__global__ __launch_bounds__(256) void gather_reg2(const u16* __restrict__ xh,
                                                   const float* __restrict__ alpha_csr,
                                                   const int* __restrict__ offs,
                                                   const int* __restrict__ csr_src,
                                                   u16* __restrict__ out) {
    constexpr int ROW = H * ONC;
    constexpr int CPP = ROW / NP;     // 256 channels per panel
    constexpr int CL  = CPP / 32;     // 8 channels per lane (uint4)
    const int bx = blockIdx.x;
    const int panel = bx % NP;
    const int wave = threadIdx.x >> 6;
    const int lane = threadIdx.x & 63;
    const int half = lane >> 5;              // which node of the pair
    const int l32  = lane & 31;
    const int n = (bx / NP) * 8 + wave * 2 + half;
    const int head = (panel * CPP) / ONC;
    const int c0 = panel * CPP + l32 * CL;
    const int beg = offs[n], end = offs[n + 1];
    const int deg = end - beg;
    const int degO = __shfl_xor(deg, 32, 64);    // partner node's degree
    const int mdeg = max(deg, degO);
    const int bsel = half << 5;
    float acc[CL];
#pragma unroll
    for (int j = 0; j < CL; j++) acc[j] = 0.f;
    for (int c = 0; c < mdeg; c += 32) {
        bool v = (c + l32) < deg;
        int myp = beg + c + l32;
        int   srcv = v ? csr_src[myp] : 0;
        float wv   = v ? alpha_csr[(size_t)myp * H + head] : 0.f;
        int cnt = min(32, mdeg - c);
#pragma unroll 8
        for (int t = 0; t < cnt; t++) {
            int   s = __shfl(srcv, bsel + t, 64);
            float w = __shfl(wv,   bsel + t, 64);
            const u16* xr = xh + (size_t)s * ROW + c0;
            uint4 val = *(const uint4*)xr;
            acc[0] = fmaf(w, bflo(val.x), acc[0]);
            acc[1] = fmaf(w, bfhi(val.x), acc[1]);
            acc[2] = fmaf(w, bflo(val.y), acc[2]);
            acc[3] = fmaf(w, bfhi(val.y), acc[3]);
            acc[4] = fmaf(w, bflo(val.z), acc[4]);
            acc[5] = fmaf(w, bfhi(val.z), acc[5]);
            acc[6] = fmaf(w, bflo(val.w), acc[6]);
            acc[7] = fmaf(w, bfhi(val.w), acc[7]);
        }
    }
    u16* orow = out + (size_t)n * ROW + c0;
    uint4 r;
    r.x = f2bf(acc[0]) | (f2bf(acc[1]) << 16);
    r.y = f2bf(acc[2]) | (f2bf(acc[3]) << 16);
    r.z = f2bf(acc[4]) | (f2bf(acc[5]) << 16);
    r.w = f2bf(acc[6]) | (f2bf(acc[7]) << 16);
    *(uint4*)orow = r;
}

// ---------------- mixture-prior quadratic table: comp_k(Z) = (a*Z + b)*Z + c ----------------
__global__ void mix_table(const float* __restrict__ pi, const float* __restrict__ mu,
                          const float* __restrict__ logsig, float* __restrict__ tab, int DK) {
    int i = blockIdx.x * blockDim.x + threadIdx.x;
    if (i >= DK) return;
    int k = i % KC;
    float p[KC]; float mx = -3.4e38f;
#pragma unroll
    for (int j = 0; j < KC; j++) { p[j] = pi[j]; mx = fmaxf(mx, p[j]); }
    float s = 0.f;
#pragma unroll
    for (int j = 0; j < KC; j++) s += expf(p[j] - mx);
    float lpi = p[k] - (mx + logf(s));
    float ls = logsig[i];
    float inv = expf(-ls);
    float inv2 = inv * inv;
    float m = mu[i];
    tab[i]          = -0.5f * inv2;                                      // a
    tab[DK + i]     = inv2 * m;                                          // b
    tab[2 * DK + i] = -0.5f * inv2 * m * m - ls - 0.5f * LOG2PI_F + lpi; // c
}

// ---------------- zixz v4: thread owns 4 channels, block covers full D (H=4) ----------------
// vectorized loads: uint2 mean + uint2 raw + float4 eps per node per thread;
// 60 mixture coeffs live in registers, amortized over NT nodes.
template <int NT, bool BF16OUT>
__global__ __launch_bounds__(256) void zixz4_kernel(const u16* __restrict__ in_agg,
                                                    const float* __restrict__ eps,
                                                    const float* __restrict__ tab,
                                                    void* __restrict__ hout_,
                                                    float* __restrict__ ixz_acc) {
    constexpr int H = H1C;
    constexpr int D = H * HIDC;       // 1024
    constexpr int DK = D * KC;
    const int tid = threadIdx.x;
    const int d0 = tid * 4;
    const int head = d0 >> 8;
    const int c = d0 & 255;
    const int moff = head * ONC + c;
    float ca[4][KC], cb[4][KC], cv[4][KC];
#pragma unroll
    for (int j = 0; j < 4; j++)
#pragma unroll
        for (int k = 0; k < KC; k++) {
            ca[j][k] = tab[(d0 + j) * KC + k];
            cb[j][k] = tab[DK + (d0 + j) * KC + k];
            cv[j][k] = tab[2 * DK + (d0 + j) * KC + k];
        }
    const int n0 = blockIdx.x * NT;
    float local = 0.f;
#pragma unroll 1
    for (int nn = 0; nn < NT; nn++) {
        int n = n0 + nn;
        const u16* orow = in_agg + (size_t)n * (H * ONC);
        uint2 vm = *(const uint2*)(orow + moff);
        uint2 vr = *(const uint2*)(orow + moff + HIDC);
        float4 ep4 = *(const float4*)(eps + (size_t)n * D + d0);
        float mean[4] = { bflo(vm.x), bfhi(vm.x), bflo(vm.y), bfhi(vm.y) };
        float raw[4]  = { bflo(vr.x), bfhi(vr.x), bflo(vr.y), bfhi(vr.y) };
        float epq[4]  = { ep4.x, ep4.y, ep4.z, ep4.w };
        float hv4[4];
#pragma unroll
        for (int j = 0; j < 4; j++) {
            float sp = fmaxf(raw[j], 0.f) + __logf(1.f + __expf(-fabsf(raw[j])));
            float stdv = sp + 1e-10f;
            float ep = epq[j];
            float Z = fmaf(stdv, ep, mean[j]);
            hv4[j] = (Z > 0.f) ? Z : (__expf(Z) - 1.f);
            float logq = fmaf(-0.5f, ep * ep, -__logf(stdv)) - 0.5f * LOG2PI_F;
            float comp[KC]; float mx = -3.4e38f;
#pragma unroll
            for (int k = 0; k < KC; k++) {
                float cval = fmaf(fmaf(ca[j][k], Z, cb[j][k]), Z, cv[j][k]);
                comp[k] = cval;
                mx = fmaxf(mx, cval);
            }
            float se = 0.f;
#pragma unroll
            for (int k = 0; k < KC; k++) se += __expf(comp[k] - mx);
            local += logq - (mx + __logf(se));
        }
        if (BF16OUT) {
            uint2 r;
            r.x = f2bf(hv4[0]) | (f2bf(hv4[1]) << 16);
            r.y = f2bf(hv4[2]) | (f2bf(hv4[3]) << 16);
            *(uint2*)((u16*)hout_ + (size_t)n * D + d0) = r;
        } else {
            *(float4*)((float*)hout_ + (size_t)n * D + d0) =
                make_float4(hv4[0], hv4[1], hv4[2], hv4[3]);
        }
    }
#pragma unroll
    for (int o = 32; o > 0; o >>= 1) local += __shfl_down(local, o, 64);
    __shared__ float red[4];
    int lane = tid & 63, wid = tid >> 6;
    if (lane == 0) red[wid] = local;
    __syncthreads();
    if (tid == 0)
        atomicAdd(ixz_acc, (red[0] + red[1] + red[2] + red[3]) * (1.0f / NN));
}

// ---------------- zixz v3 (thread-owns-channel) — kept for layer 2 (H=1) ----------------
template <int H, int NT, bool BF16OUT>
__global__ __launch_bounds__(256) void zixz3_kernel(const u16* __restrict__ in_agg,
                                                    const float* __restrict__ eps,
                                                    const float* __restrict__ tab,
                                                    void* __restrict__ hout_,
                                                    float* __restrict__ ixz_acc) {
    constexpr int D = H * HIDC;
    constexpr int DK = D * KC;
    const int tid = threadIdx.x;
    const int h = blockIdx.y;
    const int d = h * HIDC + tid;
    float ca[KC], cb[KC], cc[KC];
#pragma unroll
    for (int k = 0; k < KC; k++) {
        ca[k] = tab[d * KC + k];
        cb[k] = tab[DK + d * KC + k];
        cc[k] = tab[2 * DK + d * KC + k];
    }
    const int n0 = blockIdx.x * NT;
    float local = 0.f;
#pragma unroll 1
    for (int nn = 0; nn < NT; nn++) {
        int n = n0 + nn;
        const u16* orow = in_agg + ((size_t)n * H + h) * ONC;
        float mean = bf1(orow[tid]);
        float raw  = bf1(orow[HIDC + tid]);
        float sp = fmaxf(raw, 0.f) + __logf(1.f + __expf(-fabsf(raw)));
        float stdv = sp + 1e-10f;
        float ep = eps[(size_t)n * D + d];
        float Z = fmaf(stdv, ep, mean);
        float hv = (Z > 0.f) ? Z : (__expf(Z) - 1.f);   // elu
        if (BF16OUT) ((u16*)hout_)[(size_t)n * D + d] = (u16)f2bf(hv);
        else         ((float*)hout_)[(size_t)n * D + d] = hv;
        float logq = fmaf(-0.5f, ep * ep, -__logf(stdv)) - 0.5f * LOG2PI_F;
        float comp[KC]; float mx = -3.4e38f;
#pragma unroll
        for (int k = 0; k < KC; k++) {
            float cval = fmaf(fmaf(ca[k], Z, cb[k]), Z, cc[k]);
            comp[k] = cval;
            mx = fmaxf(mx, cval);
        }
        float se = 0.f;
#pragma unroll
        for (int k = 0; k < KC; k++) se += __expf(comp[k] - mx);
        local += logq - (mx + __logf(se));
    }
#pragma unroll
    for (int o = 32; o > 0; o >>= 1) local += __shfl_down(local, o, 64);
    __shared__ float red[4];
    int lane = tid & 63, wid = tid >> 6;
    if (lane == 0) red[wid] = local;
    __syncthreads();
    if (tid == 0) {
        atomicAdd(ixz_acc, (red[0] + red[1] + red[2] + red[3]) * (1.0f / NN));
    }
}

// ---------------- final FC ----------------
__global__ void fc_kernel(const float* __restrict__ h, const float* __restrict__ W,
                          const float* __restrict__ b, float* __restrict__ out) {
    int idx = blockIdx.x * blockDim.x + threadIdx.x;
    if (idx >= NN * OUTC) return;
    int n = idx / OUTC, o = idx - n * OUTC;
    const float* hr = h + (size_t)n * D2C;
    float acc = b[o];
#pragma unroll 8
    for (int c = 0; c < D2C; c++) acc += hr[c] * W[c * OUTC + o];
    out[idx] = acc;
}

// ---------------- launch ----------------
extern "C" void kernel_launch(void* const* d_in, const int* in_sizes, int n_in,
                              void* d_out, int out_size, void* d_ws, size_t ws_size,
                              hipStream_t stream) {
    (void)in_sizes; (void)n_in; (void)out_size; (void)ws_size;
    const float* x       = (const float*)d_in[0];
    const int*   ei      = (const int*)d_in[1];
    const float* W1      = (const float*)d_in[2];
    const float* att1    = (const float*)d_in[3];
    const float* pi1     = (const float*)d_in[4];
    const float* mu1     = (const float*)d_in[5];
    const float* logsig1 = (const float*)d_in[6];
    const float* eps1    = (const float*)d_in[7];
    const float* g1      = (const float*)d_in[8];
    const float* W2      = (const float*)d_in[9];
    const float* att2    = (const float*)d_in[10];
    const float* pi2     = (const float*)d_in[11];
    const float* mu2     = (const float*)d_in[12];
    const float* logsig2 = (const float*)d_in[13];
    const float* eps2    = (const float*)d_in[14];
    const float* g2      = (const float*)d_in[15];
    const float* Wfc     = (const float*)d_in[16];
    const float* bfc     = (const float*)d_in[17];
    float* out = (float*)d_out;

    // workspace layout
    char* ws = (char*)d_ws;
    const size_t szAB = (size_t)NN * 2048 * sizeof(float);
    char* regA = ws;
    char* regB = ws + szAB;
    size_t cur = 2 * szAB;
    auto alloc = [&](size_t bytes) -> char* {
        char* p = ws + cur;
        cur += (bytes + 255) & ~(size_t)255;
        return p;
    };
    float* alphaB   = (float*)alloc((size_t)EC * H1C * sizeof(float));  // CSR-order alpha
    float* s_i      = (float*)alloc((size_t)NN * H1C * sizeof(float));
    float* s_j      = (float*)alloc((size_t)NN * H1C * sizeof(float));
    int*   deg_i    = (int*)alloc(NN * sizeof(int));
    int*   offs     = (int*)alloc((NN + 1) * sizeof(int));
    int*   cursor   = (int*)alloc(NN * sizeof(int));
    int*   csr_src  = (int*)alloc(EC * sizeof(int));
    int*   csr_eid  = (int*)alloc(EC * sizeof(int));
    u16*   xb1     = (u16*)alloc((size_t)NN * INC * sizeof(u16));      // x in bf16
    u16*   w1t     = (u16*)alloc((size_t)2048 * 512 * sizeof(u16));    // W1^T bf16 [N][K]
    u16*   w2t     = (u16*)alloc((size_t)512 * 1024 * sizeof(u16));    // W2^T bf16 [N][K]
    float* tab1    = (float*)alloc((size_t)3 * D1C * KC * sizeof(float));
    float* tab2    = (float*)alloc((size_t)3 * D2C * KC * sizeof(float));

    // region assignments (stream-ordered reuse):
    u16*   xh1b = (u16*)regA;       // N x 2048 bf16 (GEMM1 out)
    u16*   out1 = (u16*)regB;       // N x 2048 bf16 (gather1 out)
    u16*   h1b  = (u16*)regA;       // N x 1024 bf16 (xh1b dead after gather1)
    u16*   xh2b = (u16*)regB;       // N x 512 bf16 (out1 dead after zixz1)
    u16*   out2 = (u16*)regA;       // N x 512 bf16 (h1b dead after GEMM2)
    float* h2   = (float*)(regB + (size_t)NN * 512 * sizeof(u16)); // N x 256 fp32 (after xh2b)
    float* kl_acc  = out + (size_t)NN * OUTC;      // d_out[100000]
    float* ixz_acc = kl_acc + 1;                   // d_out[100001]

    const int ZB = 256;
    // --- init accumulators / counters ---
    zero_u32<<<(NN + ZB - 1) / ZB, ZB, 0, stream>>>((unsigned*)deg_i, NN);
    zero_u32<<<(NN + ZB - 1) / ZB, ZB, 0, stream>>>((unsigned*)cursor, NN);
    zero_u32<<<1, ZB, 0, stream>>>((unsigned*)kl_acc, 2);

    // --- graph preprocessing (shared by both layers) ---
    count_deg<<<(EC + ZB - 1) / ZB, ZB, 0, stream>>>(ei, deg_i);
    scan_kernel<<<1, 1024, 0, stream>>>(deg_i, offs);
    csr_fill<<<(EC + ZB - 1) / ZB, ZB, 0, stream>>>(ei, cursor, offs, csr_src, csr_eid);

    // --- bf16 weight/input preparation + mixture tables ---
    cast_bf16<<<(NN * INC / 4 + ZB - 1) / ZB, ZB, 0, stream>>>(x, xb1, NN * INC / 4);
    transpose_cast_bf16<<<dim3(2048 / 32, 512 / 32), dim3(32, 8), 0, stream>>>(W1, w1t, 512, 2048);
    transpose_cast_bf16<<<dim3(512 / 32, 1024 / 32), dim3(32, 8), 0, stream>>>(W2, w2t, 1024, 512);
    mix_table<<<(D1C * KC + ZB - 1) / ZB, ZB, 0, stream>>>(pi1, mu1, logsig1, tab1, D1C * KC);
    mix_table<<<(D2C * KC + ZB - 1) / ZB, ZB, 0, stream>>>(pi2, mu2, logsig2, tab2, D2C * KC);

    const int MG = (NN + 127) / 128;   // 79

    // ================= layer 1 (H=4) =================
    mfma_gemm<128, 128, 32, true><<<dim3(2048 / 128, MG), 256, 0, stream>>>(xb1, w1t, xh1b, NN, 2048, 512);
    scores_bf16<H1C><<<(NN * H1C + 3) / 4, 256, 0, stream>>>(xh1b, att1, s_i, s_j);
    attn_fused<H1C, 8><<<(NN * H1C + 31) / 32, 256, 0, stream>>>(offs, csr_src, csr_eid,
                                                                 s_i, s_j, g1, alphaB, kl_acc,
                                                                 1.0f / (float)(EC * H1C));
    gather_reg2<H1C, 8><<<8 * (NN / 8), 256, 0, stream>>>(xh1b, alphaB, offs, csr_src, out1);
    zixz4_kernel<10, true><<<NN / 10, 256, 0, stream>>>(out1, eps1, tab1, (void*)h1b, ixz_acc);

    // ================= layer 2 (H=1) =================
    mfma_gemm<128, 128, 32, true><<<dim3(512 / 128, MG), 256, 0, stream>>>(h1b, w2t, xh2b, NN, 512, 1024);
    scores_bf16<H2C><<<(NN * H2C + 3) / 4, 256, 0, stream>>>(xh2b, att2, s_i, s_j);
    attn_fused<H2C, 8><<<(NN * H2C + 31) / 32, 256, 0, stream>>>(offs, csr_src, csr_eid,
                                                                 s_i, s_j, g2, alphaB, kl_acc,
                                                                 1.0f / (float)(EC * H2C));
    gather_reg2<H2C, 2><<<2 * (NN / 8), 256, 0, stream>>>(xh2b, alphaB, offs, csr_src, out2);
    zixz3_kernel<H2C, 10, false><<<dim3(NN / 10, H2C), 256, 0, stream>>>(out2, eps2, tab2, (void*)h2, ixz_acc);

    // ================= FC head =================
    fc_kernel<<<(NN * OUTC + ZB - 1) / ZB, ZB, 0, stream>>>(h2, Wfc, bfc, out);
}